// Round 22
// baseline (158.041 us; speedup 1.0000x reference)
//
#include <hip/hip_runtime.h>
#include <hip/hip_fp16.h>

#define IN_F   2048
#define OUT_F  2048
#define NNZ_   1048576
#define BATCH  8192
#define WMASK  (OUT_F * IN_F - 1)
#define TAIL_F ((size_t)6144 * OUT_F)     // d_out tail scratch (floats offset)

typedef __bf16 bf16x8 __attribute__((ext_vector_type(8)));
typedef float  f32x4  __attribute__((ext_vector_type(4)));
typedef unsigned int u32;

__device__ __forceinline__ float bfval(unsigned short b) {
    union { u32 u; float f; } t; t.u = ((u32)b) << 16; return t.f;
}
__device__ __forceinline__ unsigned short f2bf(float f) {
    union { float f; u32 u; } v; v.f = f;
    u32 u = v.u; u += 0x7FFF + ((u >> 16) & 1);   // RNE
    return (unsigned short)(u >> 16);
}
__device__ __forceinline__ float h2f(unsigned short b) {
    union { unsigned short u; __half h; } t; t.u = b; return __half2float(t.h);
}
__device__ __forceinline__ void gload_lds16(const void* g, void* l) {
    __builtin_amdgcn_global_load_lds(
        (const __attribute__((address_space(1))) unsigned int*)g,
        (__attribute__((address_space(3))) unsigned int*)l,
        16, 0, 0);
}

// ---- pass 1: per-block row histogram (blocks 0..255) + x->bf16 (rest) ----
__global__ void hist_xcvt_kernel(const int* __restrict__ coords,
                                 u32* __restrict__ gh,          // [2048][256]
                                 const float4* __restrict__ x,
                                 ushort4* __restrict__ xb) {
    if (blockIdx.x < 256) {
        __shared__ u32 lbin[2048];
        for (int i = threadIdx.x; i < 2048; i += 256) lbin[i] = 0u;
        __syncthreads();
        const int base = blockIdx.x * 4096;
#pragma unroll
        for (int j = 0; j < 16; ++j) {
            int c = coords[base + j * 256 + threadIdx.x] & WMASK;
            atomicAdd(&lbin[c >> 11], 1u);
        }
        __syncthreads();
        for (int r = threadIdx.x; r < 2048; r += 256)
            gh[r * 256 + blockIdx.x] = lbin[r];
    } else {
        const int t0     = (blockIdx.x - 256) * 256 + threadIdx.x;
        const int stride = 1536 * 256;
        for (int i = t0; i < BATCH * IN_F / 4; i += stride) {
            float4 v = x[i];
            ushort4 o;
            o.x = f2bf(v.x); o.y = f2bf(v.y); o.z = f2bf(v.z); o.w = f2bf(v.w);
            xb[i] = o;
        }
    }
}

// ---- pass 2a: exclusive cumsum over blocks per row; row totals ----
__global__ void scanA_kernel(u32* __restrict__ gh, u32* __restrict__ rt) {
    const int r = blockIdx.x * 256 + threadIdx.x;   // 8 blocks x 256 = 2048
    u32 run = 0;
    for (int b = 0; b < 256; ++b) {
        u32 t = gh[r * 256 + b];
        gh[r * 256 + b] = run;
        run += t;
    }
    rt[r] = run;
}

// ---- pass 2b: exclusive prefix over 2048 row totals -> rowbase[2049] ----
__global__ void scanB_kernel(const u32* __restrict__ rt, u32* __restrict__ rb) {
    __shared__ u32 s[2048];
    __shared__ u32 part[256];
    const int tid = threadIdx.x;
    for (int i = tid; i < 2048; i += 256) s[i] = rt[i];
    __syncthreads();
    u32 sum = 0;
#pragma unroll
    for (int j = 0; j < 8; ++j) sum += s[tid * 8 + j];
    part[tid] = sum;
    __syncthreads();
    if (tid == 0) {
        u32 run = 0;
        for (int i = 0; i < 256; ++i) { u32 t = part[i]; part[i] = run; run += t; }
    }
    __syncthreads();
    u32 run = part[tid];
#pragma unroll
    for (int j = 0; j < 8; ++j) { u32 t = s[tid * 8 + j]; s[tid * 8 + j] = run; run += t; }
    __syncthreads();
    for (int i = tid; i < 2048; i += 256) rb[i] = s[i];
    if (tid == 0) rb[2048] = NNZ_;
}

// ---- pass 3: slot each (col,w) into row-sorted arrays (no fabric atomics) ----
__global__ void place_kernel(const unsigned short* __restrict__ wbits,
                             const int* __restrict__ coords,
                             const u32* __restrict__ gh, const u32* __restrict__ rb,
                             unsigned short* __restrict__ cs, float* __restrict__ wsr) {
    __shared__ u32 cnt[2048];
    __shared__ u32 sbf, sfh;
    if (threadIdx.x == 0) { sbf = 0u; sfh = 0u; }
    __syncthreads();
    u32 mbf = 0u, mfh = 0u;
    for (int i = threadIdx.x; i < 512; i += 256) {
        unsigned short b = wbits[i];
        u32 abf = (((u32)b) << 16) & 0x7FFFFFFFu;
        u32 afh = (u32)(b & 0x7FFF);
        mbf = mbf > abf ? mbf : abf;
        mfh = mfh > afh ? mfh : afh;
    }
    atomicMax(&sbf, mbf); atomicMax(&sfh, mfh);
    __syncthreads();
    union { u32 u; float f; } tb; tb.u = sbf;
    float bmax = tb.f;
    float hmax = h2f((unsigned short)sfh);
    const int mode = (bmax > 1e-3f && bmax < 16.f) ? 0
                   : (hmax > 1e-3f && hmax < 16.f) ? 1 : 2;   // on HW: 2 (fp32)

    for (int r = threadIdx.x; r < 2048; r += 256)
        cnt[r] = rb[r] + gh[r * 256 + blockIdx.x];
    __syncthreads();

    const int base = blockIdx.x * 4096;
#pragma unroll
    for (int j = 0; j < 16; ++j) {
        int i = base + j * 256 + threadIdx.x;
        int c = coords[i] & WMASK;
        int row = c >> 11, col = c & 2047;
        float v;
        if (mode == 0)      v = bfval(wbits[i]);
        else if (mode == 1) v = h2f(wbits[i]);
        else                v = ((const float*)wbits)[i];
        u32 pos = atomicAdd(&cnt[row], 1u);   // LDS atomic (fast)
        cs[pos]  = (unsigned short)col;
        wsr[pos] = v;
    }
}

// ---- pass 4: per-row LDS fp32 accumulate + direct bf16 wb write ----
__global__ void accum_kernel(const u32* __restrict__ rb,
                             const unsigned short* __restrict__ cs,
                             const float* __restrict__ wsr,
                             ushort4* __restrict__ wb4) {
    __shared__ float lacc[8 * 2048];   // 64 KB
    const int tid = threadIdx.x;
    for (int i = tid; i < 16384; i += 256) lacc[i] = 0.f;
    __syncthreads();
#pragma unroll
    for (int j = 0; j < 8; ++j) {
        const int row = blockIdx.x * 8 + j;
        const u32 e = rb[row + 1];
        for (u32 i = rb[row] + tid; i < e; i += 256)
            atomicAdd(&lacc[j * 2048 + cs[i]], wsr[i]);   // LDS atomic
    }
    __syncthreads();
#pragma unroll
    for (int k = 0; k < 16; ++k) {
        const int e4 = k * 256 + tid;        // ushort4 index within block's 8 rows
        const int e  = e4 * 4;
        ushort4 o;
        o.x = f2bf(lacc[e]);     o.y = f2bf(lacc[e + 1]);
        o.z = f2bf(lacc[e + 2]); o.w = f2bf(lacc[e + 3]);
        wb4[(size_t)blockIdx.x * 4096 + e4] = o;
    }
}

// ---- 256x256 bf16 GEMM (r18 VERBATIM) ----
__global__ __launch_bounds__(1024, 4) void gemm256_kernel(
    const unsigned short* __restrict__ xb,
    const unsigned short* __restrict__ wb,
    float* __restrict__ out) {
    constexpr int K = IN_F;
    constexpr int NT = K / 64;

    __shared__ __align__(16) unsigned short As[2][256 * 64];
    __shared__ __align__(16) unsigned short Bs[2][256 * 64];

    const int tid  = threadIdx.x;
    const int lane = tid & 63;
    const int wave = tid >> 6;
    const int wr   = wave >> 2;
    const int wc   = wave & 3;
    const int frow = lane & 15;
    const int klan = lane >> 4;
    const int s0   = klan ^ (lane & 7);

    const int flat = blockIdx.x;
    const int swz  = (flat & 7) * 32 + (flat >> 3);
    const int tm   = swz & 31;
    const int tn   = swz >> 5;

    const unsigned short* srcA = xb + (size_t)tm * 256 * K;
    const unsigned short* srcB = wb + (size_t)tn * 256 * K;

    const int rloc  = lane >> 3;
    const int sslot = (lane & 7) ^ rloc;

    f32x4 acc[4][4] = {};

    auto stage = [&](int buf, int kt) {
        const size_t coff = (size_t)kt * 64 + sslot * 8;
#pragma unroll
        for (int c = 0; c < 2; ++c) {
            const int row = c * 128 + wave * 8;
            gload_lds16(srcA + (size_t)(row + rloc) * K + coff,
                        &As[buf][row * 64]);
        }
#pragma unroll
        for (int c = 0; c < 2; ++c) {
            const int row = c * 128 + wave * 8;
            gload_lds16(srcB + (size_t)(row + rloc) * K + coff,
                        &Bs[buf][row * 64]);
        }
    };

    auto compute = [&](int buf) {
#pragma unroll
        for (int ks = 0; ks < 2; ++ks) {
            const int sl = s0 ^ (ks * 4);
            bf16x8 af[4], bg[4];
#pragma unroll
            for (int mf = 0; mf < 4; ++mf)
                af[mf] = *(const bf16x8*)
                    &As[buf][(wr * 64 + mf * 16 + frow) * 64 + sl * 8];
#pragma unroll
            for (int nf = 0; nf < 4; ++nf)
                bg[nf] = *(const bf16x8*)
                    &Bs[buf][(wc * 64 + nf * 16 + frow) * 64 + sl * 8];
            __builtin_amdgcn_s_setprio(1);
#pragma unroll
            for (int mf = 0; mf < 4; ++mf)
#pragma unroll
                for (int nf = 0; nf < 4; ++nf)
                    acc[mf][nf] = __builtin_amdgcn_mfma_f32_16x16x32_bf16(
                        bg[nf], af[mf], acc[mf][nf], 0, 0, 0);   // swapped: D^T
            __builtin_amdgcn_s_setprio(0);
        }
    };

    stage(0, 0);
    stage(1, 1);

    for (int kt = 0; kt < NT - 2; ++kt) {
        asm volatile("s_waitcnt vmcnt(4)" ::: "memory");
        __builtin_amdgcn_s_barrier();
        compute(kt & 1);
        asm volatile("" ::: "memory");
        __builtin_amdgcn_s_barrier();
        stage(kt & 1, kt + 2);
    }
    asm volatile("s_waitcnt vmcnt(4)" ::: "memory");
    __builtin_amdgcn_s_barrier();
    compute((NT - 2) & 1);
    asm volatile("" ::: "memory");
    __builtin_amdgcn_s_barrier();
    asm volatile("s_waitcnt vmcnt(0)" ::: "memory");
    __builtin_amdgcn_s_barrier();
    compute((NT - 1) & 1);

    const int orow0 = tm * 256 + wr * 64 + frow;
    const int ocol0 = tn * 256 + wc * 64 + klan * 4;
#pragma unroll
    for (int mf = 0; mf < 4; ++mf)
#pragma unroll
        for (int nf = 0; nf < 4; ++nf) {
            float4 v;
            v.x = acc[mf][nf][0]; v.y = acc[mf][nf][1];
            v.z = acc[mf][nf][2]; v.w = acc[mf][nf][3];
            *(float4*)&out[(size_t)(orow0 + mf * 16) * OUT_F
                           + ocol0 + nf * 16] = v;
        }
}

extern "C" void kernel_launch(void* const* d_in, const int* in_sizes, int n_in,
                              void* d_out, int out_size, void* d_ws, size_t ws_size,
                              hipStream_t stream) {
    const float*          x      = (const float*)d_in[0];
    const unsigned short* wbits  = (const unsigned short*)d_in[1];  // fp32-delivered
    const int*            coords = (const int*)d_in[2];             // int32
    float*                out    = (float*)d_out;                   // fp32

    const size_t MB = 1024 * 1024;
    // ws: wb bf16 (8 MiB) | xb bf16 (32 MiB)     [ws >= 40 MiB proven r10+]
    unsigned short* wb = (unsigned short*)d_ws;
    unsigned short* xb = (unsigned short*)((char*)d_ws + 8 * MB);
    // d_out tail scratch (dead until GEMM overwrites, consumed before):
    //   gh [2048][256] u32 (2 MB) | rt u32[2048] | rb u32[2049] |
    //   cs u16[1M] (2 MB) | wsr f32[1M] (4 MB)
    u32*            gh  = (u32*)(out + TAIL_F);
    u32*            rt  = gh + 2048 * 256;
    u32*            rb  = rt + 2048;
    unsigned short* cs  = (unsigned short*)((char*)(out + TAIL_F) + 4 * MB);
    float*          wsr = (float*)((char*)(out + TAIL_F) + 8 * MB);
    (void)ws_size; (void)in_sizes; (void)n_in; (void)out_size;

    hist_xcvt_kernel<<<1792, 256, 0, stream>>>(coords, gh, (const float4*)x,
                                               (ushort4*)xb);
    scanA_kernel<<<8, 256, 0, stream>>>(gh, rt);
    scanB_kernel<<<1, 256, 0, stream>>>(rt, rb);
    place_kernel<<<256, 256, 0, stream>>>(wbits, coords, gh, rb, cs, wsr);
    accum_kernel<<<256, 256, 0, stream>>>(rb, cs, wsr, (ushort4*)wb);

    gemm256_kernel<<<256, 1024, 0, stream>>>(xb, wb, out);
}

// Round 23
// 154.128 us; speedup vs baseline: 1.0254x; 1.0254x over previous
//
#include <hip/hip_runtime.h>
#include <hip/hip_fp16.h>

#define IN_F   2048
#define OUT_F  2048
#define NNZ_   1048576
#define BATCH  8192
#define W_ROW0 6144
#define W_BASE ((size_t)W_ROW0 * OUT_F)   // W fp32 parked at out rows [6144,8192)

typedef __bf16 bf16x8 __attribute__((ext_vector_type(8)));
typedef float  f32x4  __attribute__((ext_vector_type(4)));

template <int N> struct ic { static constexpr int v = N; };

__device__ __forceinline__ float bfval(unsigned short b) {
    union { unsigned int u; float f; } t; t.u = ((unsigned int)b) << 16; return t.f;
}
__device__ __forceinline__ unsigned short f2bf(float f) {
    union { float f; unsigned int u; } v; v.f = f;
    unsigned int u = v.u; u += 0x7FFF + ((u >> 16) & 1);   // RNE
    return (unsigned short)(u >> 16);
}
__device__ __forceinline__ float h2f(unsigned short b) {
    union { unsigned short u; __half h; } t; t.u = b; return __half2float(t.h);
}
__device__ __forceinline__ void gload_lds16(const void* g, void* l) {
    __builtin_amdgcn_global_load_lds(
        (const __attribute__((address_space(1))) unsigned int*)g,
        (__attribute__((address_space(3))) unsigned int*)l,
        16, 0, 0);
}

// ---- zero W region (must globally precede scatter atomics) ----
__global__ void zero_f32_kernel(float4* __restrict__ p, int n4) {
    int s = gridDim.x * blockDim.x;
    for (int i = blockIdx.x * blockDim.x + threadIdx.x; i < n4; i += s)
        p[i] = float4{0.f, 0.f, 0.f, 0.f};
}

// ---- fused: blocks [0,512) scatter (8-deep pipelined atomics);
//      blocks [512,2048) x->bf16  (r17-proven verbatim) ----
__global__ void scatter_xcvt_kernel(const unsigned short* __restrict__ wbits,
                                    const int* __restrict__ coords,
                                    float* __restrict__ W,
                                    const float4* __restrict__ x,
                                    ushort4* __restrict__ xb) {
    if (blockIdx.x < 512) {
        __shared__ unsigned int sbf, sfh;
        if (threadIdx.x == 0) { sbf = 0u; sfh = 0u; }
        __syncthreads();
        unsigned int mbf = 0u, mfh = 0u;
        for (int i = threadIdx.x; i < 512; i += blockDim.x) {
            unsigned short b = wbits[i];
            unsigned int abf = (((unsigned int)b) << 16) & 0x7FFFFFFFu;
            unsigned int afh = (unsigned int)(b & 0x7FFF);
            mbf = mbf > abf ? mbf : abf;
            mfh = mfh > afh ? mfh : afh;
        }
        atomicMax(&sbf, mbf); atomicMax(&sfh, mfh);
        __syncthreads();
        union { unsigned int u; float f; } tb; tb.u = sbf;
        float bmax = tb.f;
        float hmax = h2f((unsigned short)sfh);
        int mode = (bmax > 1e-3f && bmax < 16.f) ? 0
                 : (hmax > 1e-3f && hmax < 16.f) ? 1 : 2;  // on HW: 2 (fp32)

        const int stride = 512 * 256;
#pragma unroll
        for (int it = 0; it < 8; ++it) {
            int i = it * stride + blockIdx.x * 256 + threadIdx.x;  // < NNZ_
            float v;
            if (mode == 0)      v = bfval(wbits[i]);
            else if (mode == 1) v = h2f(wbits[i]);
            else                v = ((const float*)wbits)[i];
            atomicAdd(&W[coords[i] & (OUT_F * IN_F - 1)], v);
        }
    } else {
        const int t0     = (blockIdx.x - 512) * 256 + threadIdx.x;
        const int stride = 1536 * 256;
        for (int i = t0; i < BATCH * IN_F / 4; i += stride) {
            float4 v = x[i];
            ushort4 o;
            o.x = f2bf(v.x); o.y = f2bf(v.y); o.z = f2bf(v.z); o.w = f2bf(v.w);
            xb[i] = o;
        }
    }
}

// ---- W fp32 -> wb bf16 ----
__global__ void f32_to_bf16_kernel(const float4* __restrict__ in,
                                   ushort4* __restrict__ out, int n4) {
    int s = gridDim.x * blockDim.x;
    for (int i = blockIdx.x * blockDim.x + threadIdx.x; i < n4; i += s) {
        float4 v = in[i];
        ushort4 o;
        o.x = f2bf(v.x); o.y = f2bf(v.y); o.z = f2bf(v.z); o.w = f2bf(v.w);
        out[i] = o;
    }
}

// ---- 256x256 bf16 GEMM, m201-style 4-phase schedule, 8 waves (2Mx4N),
//      per-wave 128x64, B-frags register-resident, counted vmcnt(6). ----
// Deadness schedule (tile kt, buf b=kt&1): B-buf b fully read in phase 0;
// A-buf b read in 32-row slices per phase (quadrants). Stages:
//   ph0 -> A-chunks 1,3 of kt+1 (buf b^1; dead since kt-1 ph3)
//   ph1 -> B-chunks 0,1 of kt+2 (buf b; dead after ph0)
//   ph2 -> B-chunks 2,3 of kt+2
//   ph3 -> A-chunks 0,2 of kt+2 (dead after ph1) + vmcnt(6) -> all kt+1 landed
__global__ __launch_bounds__(512, 2) void gemm256_kernel(
    const unsigned short* __restrict__ xb,
    const unsigned short* __restrict__ wb,
    float* __restrict__ out) {
    constexpr int K = IN_F;
    constexpr int NT = K / 64;                 // 32 K-tiles

    __shared__ __align__(16) unsigned short As[2][256 * 64];   // 64 KiB
    __shared__ __align__(16) unsigned short Bs[2][256 * 64];   // 64 KiB

    const int tid  = threadIdx.x;
    const int lane = tid & 63;
    const int wave = tid >> 6;        // 0..7
    const int wr   = wave >> 2;       // 0..1 (M half: 128 rows)
    const int wc   = wave & 3;        // 0..3 (N quarter: 64 cols)
    const int frow = lane & 15;
    const int klan = lane >> 4;
    const int s0   = klan ^ (lane & 7);

    const int flat = blockIdx.x;
    const int swz  = (flat & 7) * 32 + (flat >> 3);   // XCD swizzle
    const int tm   = swz & 31;
    const int tn   = swz >> 5;

    const unsigned short* srcA = xb + (size_t)tm * 256 * K;
    const unsigned short* srcB = wb + (size_t)tn * 256 * K;

    const int rloc  = lane >> 3;
    const int sslot = (lane & 7) ^ rloc;

    f32x4 acc[8][4] = {};

    // stage one 64-row chunk's 8-row wave stripe (1 KB) of tile kt into buf
    auto stageA = [&](int buf, int kt, int chunk) {
        const int row = chunk * 64 + wave * 8;   // wave-uniform
        gload_lds16(srcA + (size_t)(row + rloc) * K + (size_t)kt * 64 + sslot * 8,
                    &As[buf][row * 64]);
    };
    auto stageB = [&](int buf, int kt, int chunk) {
        const int row = chunk * 64 + wave * 8;
        gload_lds16(srcB + (size_t)(row + rloc) * K + (size_t)kt * 64 + sslot * 8,
                    &Bs[buf][row * 64]);
    };

    // prologue: T0 (8 chunks) + T1 (6 chunks; A1,A3 staged at kt=0 ph0)
#pragma unroll
    for (int c = 0; c < 4; ++c) stageB(0, 0, c);
    stageA(0, 0, 0); stageA(0, 0, 2); stageA(0, 0, 1); stageA(0, 0, 3);
#pragma unroll
    for (int c = 0; c < 4; ++c) stageB(1, 1, c);
    stageA(1, 1, 0); stageA(1, 1, 2);
    asm volatile("s_waitcnt vmcnt(6)" ::: "memory");   // T0 landed
    __builtin_amdgcn_s_barrier();

    for (int kt = 0; kt < NT; ++kt) {
        const int b = kt & 1;

        // B fragments for the whole K-tile (register-resident, 8 reads)
        bf16x8 bg[4][2];
#pragma unroll
        for (int nf = 0; nf < 4; ++nf)
#pragma unroll
            for (int ks = 0; ks < 2; ++ks)
                bg[nf][ks] = *(const bf16x8*)
                    &Bs[b][(wc * 64 + nf * 16 + frow) * 64 + (s0 ^ (ks * 4)) * 8];

        auto qphase = [&](auto MF0C, int stagesel) {
            constexpr int MF0 = decltype(MF0C)::v;
            bf16x8 af[2][2];
#pragma unroll
            for (int i = 0; i < 2; ++i)
#pragma unroll
                for (int ks = 0; ks < 2; ++ks)
                    af[i][ks] = *(const bf16x8*)
                        &As[b][(wr * 128 + (MF0 + i) * 16 + frow) * 64
                               + (s0 ^ (ks * 4)) * 8];
            if (stagesel == 0) {                 // ph0: A1,A3(kt+1) -> buf b^1
                if (kt + 1 < NT) { stageA(b ^ 1, kt + 1, 1); stageA(b ^ 1, kt + 1, 3); }
            } else if (stagesel == 1) {          // ph1: B0,B1(kt+2) -> buf b
                if (kt + 2 < NT) { stageB(b, kt + 2, 0); stageB(b, kt + 2, 1); }
            } else if (stagesel == 2) {          // ph2: B2,B3(kt+2)
                if (kt + 2 < NT) { stageB(b, kt + 2, 2); stageB(b, kt + 2, 3); }
            } else {                             // ph3: A0,A2(kt+2) + vmcnt
                if (kt + 2 < NT) {
                    stageA(b, kt + 2, 0); stageA(b, kt + 2, 2);
                    asm volatile("s_waitcnt vmcnt(6)" ::: "memory");
                } else if (kt + 1 < NT) {
                    asm volatile("s_waitcnt vmcnt(0)" ::: "memory");
                }
            }
            __builtin_amdgcn_s_barrier();
            asm volatile("s_waitcnt lgkmcnt(0)" ::: "memory");
            __builtin_amdgcn_s_setprio(1);
#pragma unroll
            for (int i = 0; i < 2; ++i)
#pragma unroll
                for (int nf = 0; nf < 4; ++nf)
#pragma unroll
                    for (int ks = 0; ks < 2; ++ks)
                        acc[MF0 + i][nf] = __builtin_amdgcn_mfma_f32_16x16x32_bf16(
                            bg[nf][ks], af[i][ks], acc[MF0 + i][nf], 0, 0, 0);
            __builtin_amdgcn_s_setprio(0);
            __builtin_amdgcn_s_barrier();
        };

        qphase(ic<0>{}, 0);
        qphase(ic<2>{}, 1);
        qphase(ic<4>{}, 2);
        qphase(ic<6>{}, 3);
    }

    // epilogue (swapped D, r18-validated): out-row = frag + frow,
    // out-cols = klan*4 + r (4 consecutive) -> float4 stores
    const int orow0 = tm * 256 + wr * 128 + frow;
    const int ocol0 = tn * 256 + wc * 64 + klan * 4;
#pragma unroll
    for (int mf = 0; mf < 8; ++mf)
#pragma unroll
        for (int nf = 0; nf < 4; ++nf) {
            float4 v;
            v.x = acc[mf][nf][0]; v.y = acc[mf][nf][1];
            v.z = acc[mf][nf][2]; v.w = acc[mf][nf][3];
            *(float4*)&out[(size_t)(orow0 + mf * 16) * OUT_F
                           + ocol0 + nf * 16] = v;
        }
}

extern "C" void kernel_launch(void* const* d_in, const int* in_sizes, int n_in,
                              void* d_out, int out_size, void* d_ws, size_t ws_size,
                              hipStream_t stream) {
    const float*          x      = (const float*)d_in[0];
    const unsigned short* wbits  = (const unsigned short*)d_in[1];  // fp32-delivered
    const int*            coords = (const int*)d_in[2];             // int32
    float*                out    = (float*)d_out;                   // fp32

    const size_t MB = 1024 * 1024;
    float*          W  = out + W_BASE;                            // 16 MiB, dies pre-GEMM
    unsigned short* wb = (unsigned short*)d_ws;                   // 8 MiB
    unsigned short* xb = (unsigned short*)((char*)d_ws + 8 * MB); // 32 MiB (ws>=40 proven)
    (void)ws_size; (void)in_sizes; (void)n_in; (void)out_size;

    zero_f32_kernel<<<512, 256, 0, stream>>>((float4*)W, OUT_F * IN_F / 4);
    scatter_xcvt_kernel<<<2048, 256, 0, stream>>>(
        wbits, coords, W, (const float4*)x, (ushort4*)xb);
    f32_to_bf16_kernel<<<1024, 256, 0, stream>>>(
        (const float4*)W, (ushort4*)wb, OUT_F * IN_F / 4);

    gemm256_kernel<<<256, 512, 0, stream>>>(xb, wb, out);
}

// Round 25
// 148.008 us; speedup vs baseline: 1.0678x; 1.0414x over previous
//
#include <hip/hip_runtime.h>
#include <hip/hip_fp16.h>

#define IN_F   2048
#define OUT_F  2048
#define NNZ_   1048576
#define BATCH  8192
#define W_ROW0 6144
#define W_BASE ((size_t)W_ROW0 * OUT_F)   // W fp32 parked at out rows [6144,8192)

typedef __bf16 bf16x8 __attribute__((ext_vector_type(8)));
typedef float  f32x4  __attribute__((ext_vector_type(4)));

__device__ __forceinline__ float bfval(unsigned short b) {
    union { unsigned int u; float f; } t; t.u = ((unsigned int)b) << 16; return t.f;
}
__device__ __forceinline__ unsigned short f2bf(float f) {
    union { float f; unsigned int u; } v; v.f = f;
    unsigned int u = v.u; u += 0x7FFF + ((u >> 16) & 1);   // RNE
    return (unsigned short)(u >> 16);
}
__device__ __forceinline__ float h2f(unsigned short b) {
    union { unsigned short u; __half h; } t; t.u = b; return __half2float(t.h);
}
__device__ __forceinline__ void gload_lds16(const void* g, void* l) {
    __builtin_amdgcn_global_load_lds(
        (const __attribute__((address_space(1))) unsigned int*)g,
        (__attribute__((address_space(3))) unsigned int*)l,
        16, 0, 0);
}

// ---- zero W region (must globally precede scatter atomics) ----
__global__ void zero_f32_kernel(float4* __restrict__ p, int n4) {
    int s = gridDim.x * blockDim.x;
    for (int i = blockIdx.x * blockDim.x + threadIdx.x; i < n4; i += s)
        p[i] = float4{0.f, 0.f, 0.f, 0.f};
}

// ---- fused: blocks [0,512) scatter (8-deep pipelined atomics);
//      blocks [512,2048) x->bf16  (r17-proven verbatim) ----
__global__ void scatter_xcvt_kernel(const unsigned short* __restrict__ wbits,
                                    const int* __restrict__ coords,
                                    float* __restrict__ W,
                                    const float4* __restrict__ x,
                                    ushort4* __restrict__ xb) {
    if (blockIdx.x < 512) {
        __shared__ unsigned int sbf, sfh;
        if (threadIdx.x == 0) { sbf = 0u; sfh = 0u; }
        __syncthreads();
        unsigned int mbf = 0u, mfh = 0u;
        for (int i = threadIdx.x; i < 512; i += blockDim.x) {
            unsigned short b = wbits[i];
            unsigned int abf = (((unsigned int)b) << 16) & 0x7FFFFFFFu;
            unsigned int afh = (unsigned int)(b & 0x7FFF);
            mbf = mbf > abf ? mbf : abf;
            mfh = mfh > afh ? mfh : afh;
        }
        atomicMax(&sbf, mbf); atomicMax(&sfh, mfh);
        __syncthreads();
        union { unsigned int u; float f; } tb; tb.u = sbf;
        float bmax = tb.f;
        float hmax = h2f((unsigned short)sfh);
        int mode = (bmax > 1e-3f && bmax < 16.f) ? 0
                 : (hmax > 1e-3f && hmax < 16.f) ? 1 : 2;  // on HW: 2 (fp32)

        const int stride = 512 * 256;
#pragma unroll
        for (int it = 0; it < 8; ++it) {
            int i = it * stride + blockIdx.x * 256 + threadIdx.x;  // < NNZ_
            float v;
            if (mode == 0)      v = bfval(wbits[i]);
            else if (mode == 1) v = h2f(wbits[i]);
            else                v = ((const float*)wbits)[i];
            atomicAdd(&W[coords[i] & (OUT_F * IN_F - 1)], v);
        }
    } else {
        const int t0     = (blockIdx.x - 512) * 256 + threadIdx.x;
        const int stride = 1536 * 256;
        for (int i = t0; i < BATCH * IN_F / 4; i += stride) {
            float4 v = x[i];
            ushort4 o;
            o.x = f2bf(v.x); o.y = f2bf(v.y); o.z = f2bf(v.z); o.w = f2bf(v.w);
            xb[i] = o;
        }
    }
}

// ---- W fp32 -> wb bf16 ----
__global__ void f32_to_bf16_kernel(const float4* __restrict__ in,
                                   ushort4* __restrict__ out, int n4) {
    int s = gridDim.x * blockDim.x;
    for (int i = blockIdx.x * blockDim.x + threadIdx.x; i < n4; i += s) {
        float4 v = in[i];
        ushort4 o;
        o.x = f2bf(v.x); o.y = f2bf(v.y); o.z = f2bf(v.z); o.w = f2bf(v.w);
        out[i] = o;
    }
}

// ---- 256x256 bf16 GEMM (r18 structure; epilogue uses NON-TEMPORAL stores
//      via clang ext-vector f32x4 to kill write-allocate output fetches) ----
__global__ __launch_bounds__(1024, 4) void gemm256_kernel(
    const unsigned short* __restrict__ xb,
    const unsigned short* __restrict__ wb,
    float* __restrict__ out) {
    constexpr int K = IN_F;
    constexpr int NT = K / 64;                 // 32 K-tiles

    __shared__ __align__(16) unsigned short As[2][256 * 64];   // 64 KiB
    __shared__ __align__(16) unsigned short Bs[2][256 * 64];   // 64 KiB

    const int tid  = threadIdx.x;
    const int lane = tid & 63;
    const int wave = tid >> 6;        // 0..15
    const int wr   = wave >> 2;       // M quarter
    const int wc   = wave & 3;        // N quarter
    const int frow = lane & 15;
    const int klan = lane >> 4;
    const int s0   = klan ^ (lane & 7);

    const int flat = blockIdx.x;
    const int swz  = (flat & 7) * 32 + (flat >> 3);   // XCD swizzle
    const int tm   = swz & 31;
    const int tn   = swz >> 5;

    const unsigned short* srcA = xb + (size_t)tm * 256 * K;
    const unsigned short* srcB = wb + (size_t)tn * 256 * K;

    const int rloc  = lane >> 3;
    const int sslot = (lane & 7) ^ rloc;

    f32x4 acc[4][4] = {};

    auto stage = [&](int buf, int kt) {
        const size_t coff = (size_t)kt * 64 + sslot * 8;
#pragma unroll
        for (int c = 0; c < 2; ++c) {
            const int row = c * 128 + wave * 8;
            gload_lds16(srcA + (size_t)(row + rloc) * K + coff,
                        &As[buf][row * 64]);
        }
#pragma unroll
        for (int c = 0; c < 2; ++c) {
            const int row = c * 128 + wave * 8;
            gload_lds16(srcB + (size_t)(row + rloc) * K + coff,
                        &Bs[buf][row * 64]);
        }
    };

    auto compute = [&](int buf) {
#pragma unroll
        for (int ks = 0; ks < 2; ++ks) {
            const int sl = s0 ^ (ks * 4);
            bf16x8 af[4], bg[4];
#pragma unroll
            for (int mf = 0; mf < 4; ++mf)
                af[mf] = *(const bf16x8*)
                    &As[buf][(wr * 64 + mf * 16 + frow) * 64 + sl * 8];
#pragma unroll
            for (int nf = 0; nf < 4; ++nf)
                bg[nf] = *(const bf16x8*)
                    &Bs[buf][(wc * 64 + nf * 16 + frow) * 64 + sl * 8];
            __builtin_amdgcn_s_setprio(1);
#pragma unroll
            for (int mf = 0; mf < 4; ++mf)
#pragma unroll
                for (int nf = 0; nf < 4; ++nf)
                    acc[mf][nf] = __builtin_amdgcn_mfma_f32_16x16x32_bf16(
                        bg[nf], af[mf], acc[mf][nf], 0, 0, 0);   // swapped: D^T
            __builtin_amdgcn_s_setprio(0);
        }
    };

    stage(0, 0);
    stage(1, 1);

    for (int kt = 0; kt < NT - 2; ++kt) {
        asm volatile("s_waitcnt vmcnt(4)" ::: "memory");
        __builtin_amdgcn_s_barrier();
        compute(kt & 1);
        asm volatile("" ::: "memory");
        __builtin_amdgcn_s_barrier();
        stage(kt & 1, kt + 2);
    }
    asm volatile("s_waitcnt vmcnt(4)" ::: "memory");
    __builtin_amdgcn_s_barrier();
    compute((NT - 2) & 1);
    asm volatile("" ::: "memory");
    __builtin_amdgcn_s_barrier();
    asm volatile("s_waitcnt vmcnt(0)" ::: "memory");
    __builtin_amdgcn_s_barrier();
    compute((NT - 1) & 1);

    // epilogue (swapped D): out-row = frag + frow, out-cols = klan*4 + r.
    // Non-temporal f32x4 store: out is write-only; nt bypasses allocation.
    const int orow0 = tm * 256 + wr * 64 + frow;
    const int ocol0 = tn * 256 + wc * 64 + klan * 4;
#pragma unroll
    for (int mf = 0; mf < 4; ++mf)
#pragma unroll
        for (int nf = 0; nf < 4; ++nf) {
            __builtin_nontemporal_store(acc[mf][nf],
                (f32x4*)&out[(size_t)(orow0 + mf * 16) * OUT_F
                             + ocol0 + nf * 16]);
        }
}

extern "C" void kernel_launch(void* const* d_in, const int* in_sizes, int n_in,
                              void* d_out, int out_size, void* d_ws, size_t ws_size,
                              hipStream_t stream) {
    const float*          x      = (const float*)d_in[0];
    const unsigned short* wbits  = (const unsigned short*)d_in[1];  // fp32-delivered
    const int*            coords = (const int*)d_in[2];             // int32
    float*                out    = (float*)d_out;                   // fp32

    const size_t MB = 1024 * 1024;
    float*          W  = out + W_BASE;                            // 16 MiB, dies pre-GEMM
    unsigned short* wb = (unsigned short*)d_ws;                   // 8 MiB
    unsigned short* xb = (unsigned short*)((char*)d_ws + 8 * MB); // 32 MiB (ws>=40 proven)
    (void)ws_size; (void)in_sizes; (void)n_in; (void)out_size;

    zero_f32_kernel<<<512, 256, 0, stream>>>((float4*)W, OUT_F * IN_F / 4);
    scatter_xcvt_kernel<<<2048, 256, 0, stream>>>(
        wbits, coords, W, (const float4*)x, (ushort4*)xb);
    f32_to_bf16_kernel<<<1024, 256, 0, stream>>>(
        (const float4*)W, (ushort4*)wb, OUT_F * IN_F / 4);

    gemm256_kernel<<<256, 1024, 0, stream>>>(xb, wb, out);
}

// Round 26
// 140.994 us; speedup vs baseline: 1.1209x; 1.0497x over previous
//
#include <hip/hip_runtime.h>
#include <hip/hip_fp16.h>

#define IN_F   2048
#define OUT_F  2048
#define NNZ_   1048576
#define BATCH  8192
#define W_ROW0 6144
#define W_BASE ((size_t)W_ROW0 * OUT_F)   // W fp32 parked at out rows [6144,8192)

typedef __bf16 bf16x8 __attribute__((ext_vector_type(8)));
typedef float  f32x4  __attribute__((ext_vector_type(4)));

__device__ __forceinline__ float bfval(unsigned short b) {
    union { unsigned int u; float f; } t; t.u = ((unsigned int)b) << 16; return t.f;
}
__device__ __forceinline__ unsigned short f2bf(float f) {
    union { float f; unsigned int u; } v; v.f = f;
    unsigned int u = v.u; u += 0x7FFF + ((u >> 16) & 1);   // RNE
    return (unsigned short)(u >> 16);
}
__device__ __forceinline__ float h2f(unsigned short b) {
    union { unsigned short u; __half h; } t; t.u = b; return __half2float(t.h);
}
__device__ __forceinline__ void gload_lds16(const void* g, void* l) {
    __builtin_amdgcn_global_load_lds(
        (const __attribute__((address_space(1))) unsigned int*)g,
        (__attribute__((address_space(3))) unsigned int*)l,
        16, 0, 0);
}

// ---- zero W region (must globally precede scatter atomics) ----
__global__ void zero_f32_kernel(float4* __restrict__ p, int n4) {
    int s = gridDim.x * blockDim.x;
    for (int i = blockIdx.x * blockDim.x + threadIdx.x; i < n4; i += s)
        p[i] = float4{0.f, 0.f, 0.f, 0.f};
}

// ---- fused: blocks [0,512) scatter (8-deep pipelined atomics);
//      blocks [512,2048) x->bf16  (r17-proven verbatim) ----
__global__ void scatter_xcvt_kernel(const unsigned short* __restrict__ wbits,
                                    const int* __restrict__ coords,
                                    float* __restrict__ W,
                                    const float4* __restrict__ x,
                                    ushort4* __restrict__ xb) {
    if (blockIdx.x < 512) {
        __shared__ unsigned int sbf, sfh;
        if (threadIdx.x == 0) { sbf = 0u; sfh = 0u; }
        __syncthreads();
        unsigned int mbf = 0u, mfh = 0u;
        for (int i = threadIdx.x; i < 512; i += blockDim.x) {
            unsigned short b = wbits[i];
            unsigned int abf = (((unsigned int)b) << 16) & 0x7FFFFFFFu;
            unsigned int afh = (unsigned int)(b & 0x7FFF);
            mbf = mbf > abf ? mbf : abf;
            mfh = mfh > afh ? mfh : afh;
        }
        atomicMax(&sbf, mbf); atomicMax(&sfh, mfh);
        __syncthreads();
        union { unsigned int u; float f; } tb; tb.u = sbf;
        float bmax = tb.f;
        float hmax = h2f((unsigned short)sfh);
        int mode = (bmax > 1e-3f && bmax < 16.f) ? 0
                 : (hmax > 1e-3f && hmax < 16.f) ? 1 : 2;  // on HW: 2 (fp32)

        const int stride = 512 * 256;
#pragma unroll
        for (int it = 0; it < 8; ++it) {
            int i = it * stride + blockIdx.x * 256 + threadIdx.x;  // < NNZ_
            float v;
            if (mode == 0)      v = bfval(wbits[i]);
            else if (mode == 1) v = h2f(wbits[i]);
            else                v = ((const float*)wbits)[i];
            atomicAdd(&W[coords[i] & (OUT_F * IN_F - 1)], v);
        }
    } else {
        const int t0     = (blockIdx.x - 512) * 256 + threadIdx.x;
        const int stride = 1536 * 256;
        for (int i = t0; i < BATCH * IN_F / 4; i += stride) {
            float4 v = x[i];
            ushort4 o;
            o.x = f2bf(v.x); o.y = f2bf(v.y); o.z = f2bf(v.z); o.w = f2bf(v.w);
            xb[i] = o;
        }
    }
}

// ---- W fp32 -> wb bf16 ----
__global__ void f32_to_bf16_kernel(const float4* __restrict__ in,
                                   ushort4* __restrict__ out, int n4) {
    int s = gridDim.x * blockDim.x;
    for (int i = blockIdx.x * blockDim.x + threadIdx.x; i < n4; i += s) {
        float4 v = in[i];
        ushort4 o;
        o.x = f2bf(v.x); o.y = f2bf(v.y); o.z = f2bf(v.z); o.w = f2bf(v.w);
        out[i] = o;
    }
}

// ---- 256x256 bf16 GEMM (r18 structure/epilogue; XCD mapping inverted:
//      each XCD owns a contiguous tm-chunk (A is 4x bigger than B), so
//      per-XCD L2 demand drops 33 MB -> 12 MB) ----
__global__ __launch_bounds__(1024, 4) void gemm256_kernel(
    const unsigned short* __restrict__ xb,
    const unsigned short* __restrict__ wb,
    float* __restrict__ out) {
    constexpr int K = IN_F;
    constexpr int NT = K / 64;                 // 32 K-tiles

    __shared__ __align__(16) unsigned short As[2][256 * 64];   // 64 KiB
    __shared__ __align__(16) unsigned short Bs[2][256 * 64];   // 64 KiB

    const int tid  = threadIdx.x;
    const int lane = tid & 63;
    const int wave = tid >> 6;        // 0..15
    const int wr   = wave >> 2;       // M quarter
    const int wc   = wave & 3;        // N quarter
    const int frow = lane & 15;
    const int klan = lane >> 4;
    const int s0   = klan ^ (lane & 7);

    // XCD swizzle, A-major: XCD x (flat&7) owns tm in [4x, 4x+4), all tn.
    const int flat = blockIdx.x;
    const int swz  = (flat & 7) * 32 + (flat >> 3);
    const int tm   = swz >> 3;        // 0..31, contiguous per XCD
    const int tn   = swz & 7;         // 0..7

    const unsigned short* srcA = xb + (size_t)tm * 256 * K;
    const unsigned short* srcB = wb + (size_t)tn * 256 * K;

    const int rloc  = lane >> 3;
    const int sslot = (lane & 7) ^ rloc;

    f32x4 acc[4][4] = {};

    auto stage = [&](int buf, int kt) {
        const size_t coff = (size_t)kt * 64 + sslot * 8;
#pragma unroll
        for (int c = 0; c < 2; ++c) {
            const int row = c * 128 + wave * 8;
            gload_lds16(srcA + (size_t)(row + rloc) * K + coff,
                        &As[buf][row * 64]);
        }
#pragma unroll
        for (int c = 0; c < 2; ++c) {
            const int row = c * 128 + wave * 8;
            gload_lds16(srcB + (size_t)(row + rloc) * K + coff,
                        &Bs[buf][row * 64]);
        }
    };

    auto compute = [&](int buf) {
#pragma unroll
        for (int ks = 0; ks < 2; ++ks) {
            const int sl = s0 ^ (ks * 4);
            bf16x8 af[4], bg[4];
#pragma unroll
            for (int mf = 0; mf < 4; ++mf)
                af[mf] = *(const bf16x8*)
                    &As[buf][(wr * 64 + mf * 16 + frow) * 64 + sl * 8];
#pragma unroll
            for (int nf = 0; nf < 4; ++nf)
                bg[nf] = *(const bf16x8*)
                    &Bs[buf][(wc * 64 + nf * 16 + frow) * 64 + sl * 8];
            __builtin_amdgcn_s_setprio(1);
#pragma unroll
            for (int mf = 0; mf < 4; ++mf)
#pragma unroll
                for (int nf = 0; nf < 4; ++nf)
                    acc[mf][nf] = __builtin_amdgcn_mfma_f32_16x16x32_bf16(
                        bg[nf], af[mf], acc[mf][nf], 0, 0, 0);   // swapped: D^T
            __builtin_amdgcn_s_setprio(0);
        }
    };

    stage(0, 0);
    stage(1, 1);

    for (int kt = 0; kt < NT - 2; ++kt) {
        asm volatile("s_waitcnt vmcnt(4)" ::: "memory");
        __builtin_amdgcn_s_barrier();
        compute(kt & 1);
        asm volatile("" ::: "memory");
        __builtin_amdgcn_s_barrier();
        stage(kt & 1, kt + 2);
    }
    asm volatile("s_waitcnt vmcnt(4)" ::: "memory");
    __builtin_amdgcn_s_barrier();
    compute((NT - 2) & 1);
    asm volatile("" ::: "memory");
    __builtin_amdgcn_s_barrier();
    asm volatile("s_waitcnt vmcnt(0)" ::: "memory");
    __builtin_amdgcn_s_barrier();
    compute((NT - 1) & 1);

    // epilogue (swapped D, r18-proven): plain float4 stores
    const int orow0 = tm * 256 + wr * 64 + frow;
    const int ocol0 = tn * 256 + wc * 64 + klan * 4;
#pragma unroll
    for (int mf = 0; mf < 4; ++mf)
#pragma unroll
        for (int nf = 0; nf < 4; ++nf) {
            float4 v;
            v.x = acc[mf][nf][0]; v.y = acc[mf][nf][1];
            v.z = acc[mf][nf][2]; v.w = acc[mf][nf][3];
            *(float4*)&out[(size_t)(orow0 + mf * 16) * OUT_F
                           + ocol0 + nf * 16] = v;
        }
}

extern "C" void kernel_launch(void* const* d_in, const int* in_sizes, int n_in,
                              void* d_out, int out_size, void* d_ws, size_t ws_size,
                              hipStream_t stream) {
    const float*          x      = (const float*)d_in[0];
    const unsigned short* wbits  = (const unsigned short*)d_in[1];  // fp32-delivered
    const int*            coords = (const int*)d_in[2];             // int32
    float*                out    = (float*)d_out;                   // fp32

    const size_t MB = 1024 * 1024;
    float*          W  = out + W_BASE;                            // 16 MiB, dies pre-GEMM
    unsigned short* wb = (unsigned short*)d_ws;                   // 8 MiB
    unsigned short* xb = (unsigned short*)((char*)d_ws + 8 * MB); // 32 MiB (ws>=40 proven)
    (void)ws_size; (void)in_sizes; (void)n_in; (void)out_size;

    zero_f32_kernel<<<512, 256, 0, stream>>>((float4*)W, OUT_F * IN_F / 4);
    scatter_xcvt_kernel<<<2048, 256, 0, stream>>>(
        wbits, coords, W, (const float4*)x, (ushort4*)xb);
    f32_to_bf16_kernel<<<1024, 256, 0, stream>>>(
        (const float4*)W, (ushort4*)wb, OUT_F * IN_F / 4);

    gemm256_kernel<<<256, 1024, 0, stream>>>(xb, wb, out);
}